// Round 1
// baseline (241.017 us; speedup 1.0000x reference)
//
#include <hip/hip_runtime.h>

#define NB 15
#define NV 17          // focal, cp, 15 bins
#define BLOCK 256
#define BIGGRID 2048   // 2048 blocks * 4 waves = 8192 waves = 100% occupancy

// partials layout in ws: partials[j * grid + block], j in [0,17)
// j=0: focal sum, j=1: cp sum, j=2..16: per-bin sum(t - p)

__device__ __forceinline__ void process_elem(float pk, float uk, int tk,
                                             float& facc, float& cacc,
                                             float* __restrict__ hbp)
{
    bool pos = (tk == 1);

    // focal: -alpha * (1-pt)^2 * log(pt + 1e-12), alpha = pos ? 1 : 2
    float pt = pos ? pk : 1.0f - pk;
    float om = 1.0f - pt;
    float l  = __logf(pt + 1e-12f);
    float f  = om * om * l;
    facc -= pos ? f : 2.0f * f;

    // calibration penalty
    float w   = 1.0f - uk;
    float pen = pos ? ((pk < 0.7f) ? uk * uk : 0.0f)
                    : ((pk > 0.7f) ? w * w : 0.0f);
    cacc += pen;

    // ECE histogram into per-thread LDS bins: one ds_add_f32, no return,
    // no cross-lane races (bins private per thread), stride 15 = odd -> ~2-way banks
    int b = (int)ceilf(pk * 15.0f) - 1;
    b = (b < 0) ? 0 : ((b > NB - 1) ? NB - 1 : b);
    float v = (pos ? 1.0f : 0.0f) - pk;
    atomicAdd(hbp + b, v);
}

__global__ __launch_bounds__(BLOCK) void fcl_main(
    const float* __restrict__ p_hat,
    const float* __restrict__ u_hat,
    const int*   __restrict__ targets,
    float* __restrict__ partials,
    int n4, int n)
{
    __shared__ float hb[BLOCK * NB];          // per-thread private histogram
    __shared__ float lds[BLOCK / 64][NV];     // cross-wave reduction

    const int tb = threadIdx.x * NB;
    float* hbp = &hb[tb];
    #pragma unroll
    for (int j = 0; j < NB; ++j) hbp[j] = 0.0f;

    float facc = 0.0f, cacc = 0.0f;

    const float4* __restrict__ p4 = (const float4*)p_hat;
    const float4* __restrict__ u4 = (const float4*)u_hat;
    const int4*   __restrict__ t4 = (const int4*)targets;

    const int stride = gridDim.x * blockDim.x;
    int i = blockIdx.x * blockDim.x + threadIdx.x;

    // 2x unrolled grid-stride: keeps 6 vector loads in flight
    for (; i + stride < n4; i += 2 * stride) {
        float4 p0 = p4[i];          float4 p1 = p4[i + stride];
        float4 u0 = u4[i];          float4 u1 = u4[i + stride];
        int4   t0 = t4[i];          int4   t1 = t4[i + stride];
        #pragma unroll
        for (int k = 0; k < 4; ++k)
            process_elem((&p0.x)[k], (&u0.x)[k], (&t0.x)[k], facc, cacc, hbp);
        #pragma unroll
        for (int k = 0; k < 4; ++k)
            process_elem((&p1.x)[k], (&u1.x)[k], (&t1.x)[k], facc, cacc, hbp);
    }
    if (i < n4) {
        float4 p0 = p4[i]; float4 u0 = u4[i]; int4 t0 = t4[i];
        #pragma unroll
        for (int k = 0; k < 4; ++k)
            process_elem((&p0.x)[k], (&u0.x)[k], (&t0.x)[k], facc, cacc, hbp);
    }

    // scalar tail (n not multiple of 4)
    if (blockIdx.x == 0 && threadIdx.x == 0) {
        for (int j = n4 * 4; j < n; ++j)
            process_elem(p_hat[j], u_hat[j], targets[j], facc, cacc, hbp);
    }

    // gather this thread's bins back from LDS (own writes, in-order DS pipe)
    float vals[NV];
    vals[0] = facc; vals[1] = cacc;
    #pragma unroll
    for (int j = 0; j < NB; ++j) vals[2 + j] = hbp[j];

    // wave-64 shuffle reduction of all 17 values
    #pragma unroll
    for (int off = 32; off > 0; off >>= 1) {
        #pragma unroll
        for (int j = 0; j < NV; ++j)
            vals[j] += __shfl_down(vals[j], off, 64);
    }

    const int wave = threadIdx.x >> 6;
    const int lane = threadIdx.x & 63;
    if (lane == 0) {
        #pragma unroll
        for (int j = 0; j < NV; ++j) lds[wave][j] = vals[j];
    }
    __syncthreads();

    if (threadIdx.x < NV) {
        float s = 0.0f;
        #pragma unroll
        for (int w = 0; w < BLOCK / 64; ++w) s += lds[w][threadIdx.x];
        partials[threadIdx.x * gridDim.x + blockIdx.x] = s;
    }
}

__global__ __launch_bounds__(1024) void fcl_final(
    const float* __restrict__ partials,
    float* __restrict__ out, float inv_n, int grid)
{
    const int t = threadIdx.x;   // 1024 threads; loop handles grid > 1024
    float v[NV];
    #pragma unroll
    for (int j = 0; j < NV; ++j) {
        float s = 0.0f;
        for (int g = t; g < grid; g += 1024)
            s += partials[j * grid + g];
        v[j] = s;
    }

    #pragma unroll
    for (int off = 32; off > 0; off >>= 1) {
        #pragma unroll
        for (int j = 0; j < NV; ++j)
            v[j] += __shfl_down(v[j], off, 64);
    }

    __shared__ float lds[16][NV];
    const int wave = t >> 6;
    const int lane = t & 63;
    if (lane == 0) {
        #pragma unroll
        for (int j = 0; j < NV; ++j) lds[wave][j] = v[j];
    }
    __syncthreads();

    if (t == 0) {
        float s[NV];
        #pragma unroll
        for (int j = 0; j < NV; ++j) s[j] = 0.0f;
        for (int w = 0; w < 16; ++w)
            #pragma unroll
            for (int j = 0; j < NV; ++j) s[j] += lds[w][j];
        float e = 0.0f;
        #pragma unroll
        for (int b = 0; b < NB; ++b) e += fabsf(s[2 + b]);
        out[0] = (s[0] + 6.0f * s[1] + 5.0f * e) * inv_n;
    }
}

extern "C" void kernel_launch(void* const* d_in, const int* in_sizes, int n_in,
                              void* d_out, int out_size, void* d_ws, size_t ws_size,
                              hipStream_t stream) {
    const float* p = (const float*)d_in[0];
    const float* u = (const float*)d_in[1];
    const int*   t = (const int*)d_in[2];
    float* out = (float*)d_out;
    float* ws  = (float*)d_ws;

    const int n  = in_sizes[0];
    const int n4 = n / 4;

    // use the big grid only if the workspace can hold the partials
    const int grid = (ws_size >= (size_t)(NV * BIGGRID) * sizeof(float)) ? BIGGRID : 1024;

    fcl_main<<<grid, BLOCK, 0, stream>>>(p, u, t, ws, n4, n);
    fcl_final<<<1, 1024, 0, stream>>>(ws, out, 1.0f / (float)n, grid);
}

// Round 2
// 218.604 us; speedup vs baseline: 1.1025x; 1.1025x over previous
//
#include <hip/hip_runtime.h>

#define NB 15
#define NV 17          // focal, cp, 15 bins
#define BLOCK 256
#define BIGGRID 2048   // 2048 blocks * 4 waves/block = 8192 waves = 100% occupancy

// partials layout in ws: partials[j * grid + block], j in [0,17)
// j=0: focal sum, j=1: cp sum, j=2..16: per-bin sum(t - p)

__device__ __forceinline__ void process_elem(float pk, float uk, int tk,
                                             float& facc, float& cacc,
                                             float* bins)
{
    bool pos = (tk == 1);

    // focal: -alpha * (1-pt)^2 * ln(pt + 1e-12)
    // ln(x) = log2(x) * ln2; fold ln2 into alpha constant:
    //   negalpha = pos ? -ln2 : -2*ln2
    float pt  = pos ? pk : 1.0f - pk;
    float om  = 1.0f - pt;
    float l2  = __log2f(pt + 1e-12f);
    float f   = om * om * l2;
    float na  = pos ? -0.69314718055994531f : -1.38629436111989062f;
    facc = fmaf(f, na, facc);

    // calibration penalty:
    //   pos: (pk < 0.7) ? uk^2          : 0
    //   neg: (pk > 0.7) ? (1-uk)^2      : 0
    // rewrite gate on pt:  pos: pt<0.7   neg: 1-pk<0.3 i.e. pt<0.3
    float thr = pos ? 0.7f : 0.3f;
    float s   = pos ? uk : 1.0f - uk;
    float s2  = s * s;
    float pen = (pt < thr) ? s2 : 0.0f;
    cacc += pen;

    // ECE histogram into register bins (latency-free scatter, ~3 VALU/bin)
    int b = (int)ceilf(pk * 15.0f) - 1;
    b = min(max(b, 0), NB - 1);
    float v = (pos ? 1.0f : 0.0f) - pk;
    #pragma unroll
    for (int j = 0; j < NB; ++j)
        bins[j] += (b == j) ? v : 0.0f;
}

__global__ __launch_bounds__(BLOCK) void fcl_main(
    const float* __restrict__ p_hat,
    const float* __restrict__ u_hat,
    const int*   __restrict__ targets,
    float* __restrict__ partials,
    int n4, int n)
{
    float bins[NB];
    #pragma unroll
    for (int j = 0; j < NB; ++j) bins[j] = 0.0f;
    float facc = 0.0f, cacc = 0.0f;

    const float4* __restrict__ p4 = (const float4*)p_hat;
    const float4* __restrict__ u4 = (const float4*)u_hat;
    const int4*   __restrict__ t4 = (const int4*)targets;

    const int stride = gridDim.x * blockDim.x;
    int i = blockIdx.x * blockDim.x + threadIdx.x;

    // 2x unrolled grid-stride: keeps 6 vector loads in flight
    for (; i + stride < n4; i += 2 * stride) {
        float4 p0 = p4[i];          float4 p1 = p4[i + stride];
        float4 u0 = u4[i];          float4 u1 = u4[i + stride];
        int4   t0 = t4[i];          int4   t1 = t4[i + stride];
        #pragma unroll
        for (int k = 0; k < 4; ++k)
            process_elem((&p0.x)[k], (&u0.x)[k], (&t0.x)[k], facc, cacc, bins);
        #pragma unroll
        for (int k = 0; k < 4; ++k)
            process_elem((&p1.x)[k], (&u1.x)[k], (&t1.x)[k], facc, cacc, bins);
    }
    if (i < n4) {
        float4 p0 = p4[i]; float4 u0 = u4[i]; int4 t0 = t4[i];
        #pragma unroll
        for (int k = 0; k < 4; ++k)
            process_elem((&p0.x)[k], (&u0.x)[k], (&t0.x)[k], facc, cacc, bins);
    }

    // scalar tail (n not multiple of 4)
    if (blockIdx.x == 0 && threadIdx.x == 0) {
        for (int j = n4 * 4; j < n; ++j)
            process_elem(p_hat[j], u_hat[j], targets[j], facc, cacc, bins);
    }

    // wave-64 shuffle reduction of all 17 values
    float vals[NV];
    vals[0] = facc; vals[1] = cacc;
    #pragma unroll
    for (int j = 0; j < NB; ++j) vals[2 + j] = bins[j];

    #pragma unroll
    for (int off = 32; off > 0; off >>= 1) {
        #pragma unroll
        for (int j = 0; j < NV; ++j)
            vals[j] += __shfl_down(vals[j], off, 64);
    }

    __shared__ float lds[BLOCK / 64][NV];
    const int wave = threadIdx.x >> 6;
    const int lane = threadIdx.x & 63;
    if (lane == 0) {
        #pragma unroll
        for (int j = 0; j < NV; ++j) lds[wave][j] = vals[j];
    }
    __syncthreads();

    if (threadIdx.x < NV) {
        float s = 0.0f;
        #pragma unroll
        for (int w = 0; w < BLOCK / 64; ++w) s += lds[w][threadIdx.x];
        partials[threadIdx.x * gridDim.x + blockIdx.x] = s;
    }
}

__global__ __launch_bounds__(1024) void fcl_final(
    const float* __restrict__ partials,
    float* __restrict__ out, float inv_n, int grid)
{
    const int t = threadIdx.x;   // 1024 threads; loop handles grid > 1024
    float v[NV];
    #pragma unroll
    for (int j = 0; j < NV; ++j) {
        float s = 0.0f;
        for (int g = t; g < grid; g += 1024)
            s += partials[j * grid + g];
        v[j] = s;
    }

    #pragma unroll
    for (int off = 32; off > 0; off >>= 1) {
        #pragma unroll
        for (int j = 0; j < NV; ++j)
            v[j] += __shfl_down(v[j], off, 64);
    }

    __shared__ float lds[16][NV];
    const int wave = t >> 6;
    const int lane = t & 63;
    if (lane == 0) {
        #pragma unroll
        for (int j = 0; j < NV; ++j) lds[wave][j] = v[j];
    }
    __syncthreads();

    if (t == 0) {
        float s[NV];
        #pragma unroll
        for (int j = 0; j < NV; ++j) s[j] = 0.0f;
        for (int w = 0; w < 16; ++w)
            #pragma unroll
            for (int j = 0; j < NV; ++j) s[j] += lds[w][j];
        float e = 0.0f;
        #pragma unroll
        for (int b = 0; b < NB; ++b) e += fabsf(s[2 + b]);
        out[0] = (s[0] + 6.0f * s[1] + 5.0f * e) * inv_n;
    }
}

extern "C" void kernel_launch(void* const* d_in, const int* in_sizes, int n_in,
                              void* d_out, int out_size, void* d_ws, size_t ws_size,
                              hipStream_t stream) {
    const float* p = (const float*)d_in[0];
    const float* u = (const float*)d_in[1];
    const int*   t = (const int*)d_in[2];
    float* out = (float*)d_out;
    float* ws  = (float*)d_ws;

    const int n  = in_sizes[0];
    const int n4 = n / 4;

    // use the big grid only if the workspace can hold the partials
    const int grid = (ws_size >= (size_t)(NV * BIGGRID) * sizeof(float)) ? BIGGRID : 1024;

    fcl_main<<<grid, BLOCK, 0, stream>>>(p, u, t, ws, n4, n);
    fcl_final<<<1, 1024, 0, stream>>>(ws, out, 1.0f / (float)n, grid);
}

// Round 3
// 217.280 us; speedup vs baseline: 1.1092x; 1.0061x over previous
//
#include <hip/hip_runtime.h>

#define NB 15
#define NV 17          // focal, cp, 15 bins
#define BLOCK 256
#define BIGGRID 2048   // 2048 blocks * 4 waves/block = 8192 waves

// partials layout in ws: partials[j * grid + block], j in [0,17)
// j=0: focal sum, j=1: cp sum, j=2..16: per-bin sum(t - p)

__device__ __forceinline__ void process_elem(float pk, float uk, int tk,
                                             float& facc, float& cacc,
                                             float* bins)
{
    bool pos = (tk == 1);

    // focal: -alpha * (1-pt)^2 * ln(pt + 1e-12)
    // ln(x) = log2(x) * ln2; fold ln2 into alpha: na = pos ? -ln2 : -2*ln2
    float pt  = pos ? pk : 1.0f - pk;
    float om  = 1.0f - pt;
    float l2  = __log2f(pt + 1e-12f);
    float f   = om * om * l2;
    float na  = pos ? -0.69314718055994531f : -1.38629436111989062f;
    facc = fmaf(f, na, facc);

    // calibration penalty, gate rewritten on pt:
    //   pos: pk<0.7  <=> pt<0.7 ; neg: pk>0.7 <=> pt<0.3
    float thr = pos ? 0.7f : 0.3f;
    float s   = pos ? uk : 1.0f - uk;
    float s2  = s * s;
    float pen = (pt < thr) ? s2 : 0.0f;
    cacc += pen;

    // ECE histogram into register bins (latency-free scatter)
    // keep exact ceil form: floor-rewrite flips fp32 boundary cases vs reference
    int b = (int)ceilf(pk * 15.0f) - 1;
    b = min(max(b, 0), NB - 1);
    float v = (pos ? 1.0f : 0.0f) - pk;
    #pragma unroll
    for (int j = 0; j < NB; ++j)
        bins[j] += (b == j) ? v : 0.0f;
}

__global__ __launch_bounds__(BLOCK) void fcl_main(
    const float* __restrict__ p_hat,
    const float* __restrict__ u_hat,
    const int*   __restrict__ targets,
    float* __restrict__ partials,
    int n4, int n)
{
    float bins[NB];
    #pragma unroll
    for (int j = 0; j < NB; ++j) bins[j] = 0.0f;
    float facc = 0.0f, cacc = 0.0f;

    const float4* __restrict__ p4 = (const float4*)p_hat;
    const float4* __restrict__ u4 = (const float4*)u_hat;
    const int4*   __restrict__ t4 = (const int4*)targets;

    const int stride = gridDim.x * blockDim.x;
    const int tid0   = blockIdx.x * blockDim.x + threadIdx.x;

    // -------- 3-stage register prefetch pipeline (depth 2) --------
    // While batch A is processed, batches B and C are in flight.
    // Keeps ~3-6 KB per wave continuously outstanding instead of the
    // load->drain->compute convoy the compiler emitted (VGPR was 36;
    // it never pipelined across iterations).
    float4 pA, uA, pB, uB, pC, uC;
    int4   tA, tB, tC;

    int  iA = tid0;
    int  iB = iA + stride;
    bool hA = iA < n4;
    bool hB = iB < n4;
    if (hA) { pA = p4[iA]; uA = u4[iA]; tA = t4[iA]; }
    if (hB) { pB = p4[iB]; uB = u4[iB]; tB = t4[iB]; }

    int inx = iB + stride;
    while (hA) {
        // prefetch stage n+2
        bool hC = inx < n4;
        if (hC) { pC = p4[inx]; uC = u4[inx]; tC = t4[inx]; }

        // process stage n
        #pragma unroll
        for (int k = 0; k < 4; ++k)
            process_elem((&pA.x)[k], (&uA.x)[k], (&tA.x)[k], facc, cacc, bins);

        // rotate
        pA = pB; uA = uB; tA = tB; hA = hB;
        pB = pC; uB = uC; tB = tC; hB = hC;
        inx += stride;
    }

    // scalar tail (n not multiple of 4)
    if (blockIdx.x == 0 && threadIdx.x == 0) {
        for (int j = n4 * 4; j < n; ++j)
            process_elem(p_hat[j], u_hat[j], targets[j], facc, cacc, bins);
    }

    // wave-64 shuffle reduction of all 17 values
    float vals[NV];
    vals[0] = facc; vals[1] = cacc;
    #pragma unroll
    for (int j = 0; j < NB; ++j) vals[2 + j] = bins[j];

    #pragma unroll
    for (int off = 32; off > 0; off >>= 1) {
        #pragma unroll
        for (int j = 0; j < NV; ++j)
            vals[j] += __shfl_down(vals[j], off, 64);
    }

    __shared__ float lds[BLOCK / 64][NV];
    const int wave = threadIdx.x >> 6;
    const int lane = threadIdx.x & 63;
    if (lane == 0) {
        #pragma unroll
        for (int j = 0; j < NV; ++j) lds[wave][j] = vals[j];
    }
    __syncthreads();

    if (threadIdx.x < NV) {
        float s = 0.0f;
        #pragma unroll
        for (int w = 0; w < BLOCK / 64; ++w) s += lds[w][threadIdx.x];
        partials[threadIdx.x * gridDim.x + blockIdx.x] = s;
    }
}

__global__ __launch_bounds__(1024) void fcl_final(
    const float* __restrict__ partials,
    float* __restrict__ out, float inv_n, int grid)
{
    const int t = threadIdx.x;   // 1024 threads; loop handles grid > 1024
    float v[NV];
    #pragma unroll
    for (int j = 0; j < NV; ++j) {
        float s = 0.0f;
        for (int g = t; g < grid; g += 1024)
            s += partials[j * grid + g];
        v[j] = s;
    }

    #pragma unroll
    for (int off = 32; off > 0; off >>= 1) {
        #pragma unroll
        for (int j = 0; j < NV; ++j)
            v[j] += __shfl_down(v[j], off, 64);
    }

    __shared__ float lds[16][NV];
    const int wave = t >> 6;
    const int lane = t & 63;
    if (lane == 0) {
        #pragma unroll
        for (int j = 0; j < NV; ++j) lds[wave][j] = v[j];
    }
    __syncthreads();

    if (t == 0) {
        float s[NV];
        #pragma unroll
        for (int j = 0; j < NV; ++j) s[j] = 0.0f;
        for (int w = 0; w < 16; ++w)
            #pragma unroll
            for (int j = 0; j < NV; ++j) s[j] += lds[w][j];
        float e = 0.0f;
        #pragma unroll
        for (int b = 0; b < NB; ++b) e += fabsf(s[2 + b]);
        out[0] = (s[0] + 6.0f * s[1] + 5.0f * e) * inv_n;
    }
}

extern "C" void kernel_launch(void* const* d_in, const int* in_sizes, int n_in,
                              void* d_out, int out_size, void* d_ws, size_t ws_size,
                              hipStream_t stream) {
    const float* p = (const float*)d_in[0];
    const float* u = (const float*)d_in[1];
    const int*   t = (const int*)d_in[2];
    float* out = (float*)d_out;
    float* ws  = (float*)d_ws;

    const int n  = in_sizes[0];
    const int n4 = n / 4;

    // use the big grid only if the workspace can hold the partials
    const int grid = (ws_size >= (size_t)(NV * BIGGRID) * sizeof(float)) ? BIGGRID : 1024;

    fcl_main<<<grid, BLOCK, 0, stream>>>(p, u, t, ws, n4, n);
    fcl_final<<<1, 1024, 0, stream>>>(ws, out, 1.0f / (float)n, grid);
}

// Round 4
// 214.797 us; speedup vs baseline: 1.1221x; 1.0116x over previous
//
#include <hip/hip_runtime.h>

#define NB 15
#define NV 17          // focal, cp, 15 bins
#define BLOCK 256
#define BIGGRID 2048   // 2048 blocks * 4 waves/block = 8192 waves

// partials layout in ws: partials[j * grid + block], j in [0,17)
// j=0: focal sum, j=1: cp sum, j=2..16: per-bin sum(t - p)

__device__ __forceinline__ void process_elem(float pk, float uk, int tk,
                                             float& facc, float& cacc,
                                             float* bins)
{
    bool pos = (tk == 1);

    // focal: -alpha * (1-pt)^2 * ln(pt + 1e-12)
    // ln(x) = log2(x) * ln2; fold ln2 into alpha: na = pos ? -ln2 : -2*ln2
    float pt  = pos ? pk : 1.0f - pk;
    float om  = 1.0f - pt;
    float l2  = __log2f(pt + 1e-12f);
    float f   = om * om * l2;
    float na  = pos ? -0.69314718055994531f : -1.38629436111989062f;
    facc = fmaf(f, na, facc);

    // calibration penalty, gate rewritten on pt:
    //   pos: pk<0.7  <=> pt<0.7 ; neg: pk>0.7 <=> pt<0.3
    float thr = pos ? 0.7f : 0.3f;
    float s   = pos ? uk : 1.0f - uk;
    float s2  = s * s;
    float pen = (pt < thr) ? s2 : 0.0f;
    cacc += pen;

    // ECE histogram into register bins (latency-free scatter)
    // keep exact ceil form: floor-rewrite flips fp32 boundary cases vs reference
    int b = (int)ceilf(pk * 15.0f) - 1;
    b = min(max(b, 0), NB - 1);
    float v = (pos ? 1.0f : 0.0f) - pk;
    #pragma unroll
    for (int j = 0; j < NB; ++j)
        bins[j] += (b == j) ? v : 0.0f;
}

__device__ __forceinline__ void process4(const float4& p, const float4& u,
                                         const int4& t,
                                         float& facc, float& cacc, float* bins)
{
    #pragma unroll
    for (int k = 0; k < 4; ++k)
        process_elem((&p.x)[k], (&u.x)[k], (&t.x)[k], facc, cacc, bins);
}

__global__ __launch_bounds__(BLOCK) void fcl_main(
    const float* __restrict__ p_hat,
    const float* __restrict__ u_hat,
    const int*   __restrict__ targets,
    float* __restrict__ partials,
    int n4, int n)
{
    float bins[NB];
    #pragma unroll
    for (int j = 0; j < NB; ++j) bins[j] = 0.0f;
    float facc = 0.0f, cacc = 0.0f;

    const float4* __restrict__ p4 = (const float4*)p_hat;
    const float4* __restrict__ u4 = (const float4*)u_hat;
    const int4*   __restrict__ t4 = (const int4*)targets;

    const int stride = gridDim.x * blockDim.x;
    const int tid0   = blockIdx.x * blockDim.x + threadIdx.x;
    const int rounds = n4 / stride;   // full rounds: every thread in-bounds

    int i = tid0;
    if (rounds > 0) {
        // prologue: batch 0
        float4 pA = p4[i], uA = u4[i];
        int4   tA = t4[i];

        // steady state: prefetch r+1 (UNCONDITIONAL -- always in bounds),
        // fence the scheduler so the loads cannot be sunk below the compute,
        // then process r while the prefetch is in flight (vmcnt(3) wait).
        for (int r = 0; r + 1 < rounds; ++r) {
            const int j = i + stride;
            float4 pB = p4[j], uB = u4[j];
            int4   tB = t4[j];
            __builtin_amdgcn_sched_barrier(0);   // loads stay ABOVE this line
            process4(pA, uA, tA, facc, cacc, bins);
            pA = pB; uA = uB; tA = tB;
            i = j;
        }
        process4(pA, uA, tA, facc, cacc, bins);
        i += stride;
    }

    // remainder vec batches (n4 % stride != 0)
    while (i < n4) {
        float4 p0 = p4[i], u0 = u4[i];
        int4   t0 = t4[i];
        process4(p0, u0, t0, facc, cacc, bins);
        i += stride;
    }

    // scalar tail (n not multiple of 4)
    if (blockIdx.x == 0 && threadIdx.x == 0) {
        for (int j = n4 * 4; j < n; ++j)
            process_elem(p_hat[j], u_hat[j], targets[j], facc, cacc, bins);
    }

    // wave-64 shuffle reduction of all 17 values
    float vals[NV];
    vals[0] = facc; vals[1] = cacc;
    #pragma unroll
    for (int j = 0; j < NB; ++j) vals[2 + j] = bins[j];

    #pragma unroll
    for (int off = 32; off > 0; off >>= 1) {
        #pragma unroll
        for (int j = 0; j < NV; ++j)
            vals[j] += __shfl_down(vals[j], off, 64);
    }

    __shared__ float lds[BLOCK / 64][NV];
    const int wave = threadIdx.x >> 6;
    const int lane = threadIdx.x & 63;
    if (lane == 0) {
        #pragma unroll
        for (int j = 0; j < NV; ++j) lds[wave][j] = vals[j];
    }
    __syncthreads();

    if (threadIdx.x < NV) {
        float s = 0.0f;
        #pragma unroll
        for (int w = 0; w < BLOCK / 64; ++w) s += lds[w][threadIdx.x];
        partials[threadIdx.x * gridDim.x + blockIdx.x] = s;
    }
}

__global__ __launch_bounds__(1024) void fcl_final(
    const float* __restrict__ partials,
    float* __restrict__ out, float inv_n, int grid)
{
    const int t = threadIdx.x;   // 1024 threads; loop handles grid > 1024
    float v[NV];
    #pragma unroll
    for (int j = 0; j < NV; ++j) {
        float s = 0.0f;
        for (int g = t; g < grid; g += 1024)
            s += partials[j * grid + g];
        v[j] = s;
    }

    #pragma unroll
    for (int off = 32; off > 0; off >>= 1) {
        #pragma unroll
        for (int j = 0; j < NV; ++j)
            v[j] += __shfl_down(v[j], off, 64);
    }

    __shared__ float lds[16][NV];
    const int wave = t >> 6;
    const int lane = t & 63;
    if (lane == 0) {
        #pragma unroll
        for (int j = 0; j < NV; ++j) lds[wave][j] = v[j];
    }
    __syncthreads();

    if (t == 0) {
        float s[NV];
        #pragma unroll
        for (int j = 0; j < NV; ++j) s[j] = 0.0f;
        for (int w = 0; w < 16; ++w)
            #pragma unroll
            for (int j = 0; j < NV; ++j) s[j] += lds[w][j];
        float e = 0.0f;
        #pragma unroll
        for (int b = 0; b < NB; ++b) e += fabsf(s[2 + b]);
        out[0] = (s[0] + 6.0f * s[1] + 5.0f * e) * inv_n;
    }
}

extern "C" void kernel_launch(void* const* d_in, const int* in_sizes, int n_in,
                              void* d_out, int out_size, void* d_ws, size_t ws_size,
                              hipStream_t stream) {
    const float* p = (const float*)d_in[0];
    const float* u = (const float*)d_in[1];
    const int*   t = (const int*)d_in[2];
    float* out = (float*)d_out;
    float* ws  = (float*)d_ws;

    const int n  = in_sizes[0];
    const int n4 = n / 4;

    // use the big grid only if the workspace can hold the partials
    const int grid = (ws_size >= (size_t)(NV * BIGGRID) * sizeof(float)) ? BIGGRID : 1024;

    fcl_main<<<grid, BLOCK, 0, stream>>>(p, u, t, ws, n4, n);
    fcl_final<<<1, 1024, 0, stream>>>(ws, out, 1.0f / (float)n, grid);
}